// Round 3
// baseline (50.797 us; speedup 1.0000x reference)
//
#include <hip/hip_runtime.h>
#include <hip/hip_cooperative_groups.h>

namespace cg = cooperative_groups;

// GaussianKernelLoss on MI355X — single cooperative kernel (1 graph node).
// 128 blocks x 1024 threads; each block handles 4 landmarks in 256-thread
// slices. Per-slice: separable col/row float4 tables in LDS, bbox-limited
// inner loop, ws[bn] = num/(den+1e-8). grid.sync(), then block 0 reduces the
// 512 per-landmark values and writes out[0] (plain store; no atomics, no memset).

#define BB 32
#define NN 16
#define HH 256
#define WW 256
#define BN (BB * NN)
#define NBLK 128
#define TPB 1024

__global__ __launch_bounds__(TPB) void gkl_fused(
    const float* __restrict__ pred,   // [B,N,2]
    const float* __restrict__ tgt,    // [B,N,2]
    const float* __restrict__ vis,    // [B,N]
    const float* __restrict__ cgr,    // [2,H,W]
    float* __restrict__ ws,           // [BN]
    float* __restrict__ out)          // [1]
{
    const int s  = threadIdx.x >> 8;        // slice 0..3
    const int t  = threadIdx.x & 255;       // thread within slice
    const int bn = (blockIdx.x << 2) + s;   // landmark id 0..511

    __shared__ float4 colA[4][128];
    __shared__ float4 rowA[4][128];
    __shared__ float  s_n[4][4], s_d[4][4]; // also reused as 16-float scratch in phase B

    const bool visb = vis[bn] >= 0.5f;      // invisible => contributes exactly 0

    int i_lo = 0, bw = 0, bh = 0;
    if (visb) {
        const float tx = tgt[bn * 2 + 0], ty = tgt[bn * 2 + 1];
        const float px = pred[bn * 2 + 0], py = pred[bn * 2 + 1];

        // Conservative bbox: w == 0 outside radius 0.2 (+/-1 px FP margin).
        const float R = 0.2f;
        const int j_lo = max(0,      (int)floorf((tx - R) * 255.0f) - 1);
        const int j_hi = min(WW - 1, (int)ceilf ((tx + R) * 255.0f) + 1);
        i_lo           = max(0,      (int)floorf((ty - R) * 255.0f) - 1);
        const int i_hi = min(HH - 1, (int)ceilf ((ty + R) * 255.0f) + 1);
        bw = j_hi - j_lo + 1;   // <= 106
        bh = i_hi - i_lo + 1;   // <= 106

        // Separable precompute: threads 0..127 columns, 128..255 rows.
        if (t < 128) {
            if (t < bw) {
                const float x   = cgr[j_lo + t];             // x-coords: row 0, plane 0
                const float dxt = x - tx, dxp = x - px;
                colA[s][t] = make_float4(dxt * dxt, expf(-50.0f * dxt * dxt),
                                         dxp * dxp, 0.0f);
            }
        } else {
            const int r = t - 128;
            if (r < bh) {
                const float y   = cgr[HH * WW + (i_lo + r) * WW];  // y-coords: col 0, plane 1
                const float dyt = y - ty, dyp = y - py;
                rowA[s][r] = make_float4(dyt * dyt, expf(-50.0f * dyt * dyt),
                                         dyp * dyp, 0.0f);
            }
        }
    }
    __syncthreads();

    const int lane = t & 63;
    const int wid  = t >> 6;                // wave within slice, 0..3

    float num = 0.0f, den = 0.0f;
    if (visb) {
        for (int r = wid; r < bh; r += 4) {
            const float4 rv = rowA[s][r];            // wave-uniform LDS broadcast
            for (int c = lane; c < bw; c += 64) {
                const float4 cv = colA[s][c];
                const float d2t = cv.x + rv.x;
                float w = cv.y * rv.y;
                w = (sqrtf(d2t) <= 0.2f) ? w : 0.0f; // exact reference mask
                const float dp = sqrtf(cv.z + rv.z);
                num = fmaf(w, dp, num);
                den += w;
            }
        }
    }
    for (int off = 32; off > 0; off >>= 1) {
        num += __shfl_down(num, off);
        den += __shfl_down(den, off);
    }
    if (lane == 0) { s_n[s][wid] = num; s_d[s][wid] = den; }
    __syncthreads();
    if (t == 0) {
        const float nt = s_n[s][0] + s_n[s][1] + s_n[s][2] + s_n[s][3];
        const float dt = s_d[s][0] + s_d[s][1] + s_d[s][2] + s_d[s][3];
        ws[bn] = visb ? (nt / (dt + 1e-8f)) : 0.0f;
    }

    cg::this_grid().sync();

    // Phase B: block 0 reduces the 512 per-landmark values.
    if (blockIdx.x == 0) {
        const int tid = threadIdx.x;        // 1024 threads = 16 waves
        float v = (tid < BN) ? ws[tid] : 0.0f;
        for (int off = 32; off > 0; off >>= 1) v += __shfl_down(v, off);
        float* sred = &s_n[0][0];           // 16-float scratch (done with s_n)
        __syncthreads();
        if ((tid & 63) == 0) sred[tid >> 6] = v;
        __syncthreads();
        if (tid == 0) {
            float tot = 0.0f;
            #pragma unroll
            for (int i = 0; i < 16; ++i) tot += sred[i];
            out[0] = tot * (1.0f / 512.0f); // fp32(512 + 1e-8) == 512
        }
    }
}

extern "C" void kernel_launch(void* const* d_in, const int* in_sizes, int n_in,
                              void* d_out, int out_size, void* d_ws, size_t ws_size,
                              hipStream_t stream) {
    const float* pred = (const float*)d_in[0];
    const float* tgt  = (const float*)d_in[1];
    const float* vis  = (const float*)d_in[2];
    const float* cgr  = (const float*)d_in[3];
    float* ws  = (float*)d_ws;
    float* out = (float*)d_out;

    void* args[] = { (void*)&pred, (void*)&tgt, (void*)&vis, (void*)&cgr,
                     (void*)&ws, (void*)&out };
    hipLaunchCooperativeKernel((const void*)gkl_fused, dim3(NBLK), dim3(TPB),
                               args, 0, stream);
}

// Round 6
// 21.911 us; speedup vs baseline: 2.3184x; 2.3184x over previous
//
#include <hip/hip_runtime.h>

// GaussianKernelLoss on MI355X — ONE kernel node, counter-free completion.
// Each of 128 blocks (4 landmark slices of 256 threads) publishes its partial
// as a self-validating 64-bit pair (bits, ~bits) via 64-bit atomicExch.
// Block 0 spin-reads every slot with a 64-bit atomicAdd(slot,0) (RMW at the
// coherence point: always fresh, never torn) until hi == ~lo, then reduces and
// plain-stores out[0]. Init-proof: poison 0xAA.. and zeros fail the pair check;
// a prior replay's pairs validate but hold the identical (deterministic) value.
// R5's counter mod-128 trick was wrong: poisoned counter starts = 42 (mod 128),
// so the "last" block fired 42 publications early — matching absmax ~0.1.

#define BB 32
#define NN 16
#define HH 256
#define WW 256
#define BN (BB * NN)
#define NBLK 128
#define TPB 1024

__global__ __launch_bounds__(TPB) void gkl_fused(
    const float* __restrict__ pred,   // [B,N,2]
    const float* __restrict__ tgt,    // [B,N,2]
    const float* __restrict__ vis,    // [B,N]
    const float* __restrict__ cgr,    // [2,H,W]
    unsigned long long* __restrict__ slots, // [NBLK] (value, ~value) pairs
    float* __restrict__ out)          // [1]
{
    const int s  = threadIdx.x >> 8;        // slice 0..3
    const int t  = threadIdx.x & 255;       // thread within slice
    const int bn = (blockIdx.x << 2) + s;   // landmark id 0..511

    __shared__ float4 colA[4][128];
    __shared__ float4 rowA[4][128];
    __shared__ float  s_n[4][4], s_d[4][4];
    __shared__ float  s_per[4];
    __shared__ float  s_fin[2];

    const bool visb = vis[bn] >= 0.5f;      // invisible => contributes exactly 0

    int bw = 0, bh = 0;
    if (visb) {
        const float tx = tgt[bn * 2 + 0], ty = tgt[bn * 2 + 1];
        const float px = pred[bn * 2 + 0], py = pred[bn * 2 + 1];

        // Conservative bbox: w == 0 outside radius 0.2 (+/-1 px FP margin).
        const float R = 0.2f;
        const int j_lo = max(0,      (int)floorf((tx - R) * 255.0f) - 1);
        const int j_hi = min(WW - 1, (int)ceilf ((tx + R) * 255.0f) + 1);
        const int i_lo = max(0,      (int)floorf((ty - R) * 255.0f) - 1);
        const int i_hi = min(HH - 1, (int)ceilf ((ty + R) * 255.0f) + 1);
        bw = j_hi - j_lo + 1;   // <= 106
        bh = i_hi - i_lo + 1;   // <= 106

        // Separable precompute: threads 0..127 columns, 128..255 rows.
        if (t < 128) {
            if (t < bw) {
                const float x   = cgr[j_lo + t];             // x-coords: row 0, plane 0
                const float dxt = x - tx, dxp = x - px;
                colA[s][t] = make_float4(dxt * dxt, expf(-50.0f * dxt * dxt),
                                         dxp * dxp, 0.0f);
            }
        } else {
            const int r = t - 128;
            if (r < bh) {
                const float y   = cgr[HH * WW + (i_lo + r) * WW]; // y-coords: col 0, plane 1
                const float dyt = y - ty, dyp = y - py;
                rowA[s][r] = make_float4(dyt * dyt, expf(-50.0f * dyt * dyt),
                                         dyp * dyp, 0.0f);
            }
        }
    }
    __syncthreads();

    const int lane = t & 63;
    const int wid  = t >> 6;                // wave within slice, 0..3

    float num = 0.0f, den = 0.0f;
    if (visb) {
        for (int r = wid; r < bh; r += 4) {
            const float4 rv = rowA[s][r];            // wave-uniform LDS broadcast
            for (int c = lane; c < bw; c += 64) {
                const float4 cv = colA[s][c];
                const float d2t = cv.x + rv.x;
                float w = cv.y * rv.y;
                w = (sqrtf(d2t) <= 0.2f) ? w : 0.0f; // exact reference mask
                const float dp = sqrtf(cv.z + rv.z);
                num = fmaf(w, dp, num);
                den += w;
            }
        }
    }
    for (int off = 32; off > 0; off >>= 1) {
        num += __shfl_down(num, off);
        den += __shfl_down(den, off);
    }
    if (lane == 0) { s_n[s][wid] = num; s_d[s][wid] = den; }
    __syncthreads();
    if (t == 0) {
        const float nt = s_n[s][0] + s_n[s][1] + s_n[s][2] + s_n[s][3];
        const float dt = s_d[s][0] + s_d[s][1] + s_d[s][2] + s_d[s][3];
        s_per[s] = visb ? (nt / (dt + 1e-8f)) : 0.0f;
    }
    __syncthreads();

    // Publish block partial as a self-validating (bits, ~bits) 64-bit pair.
    if (threadIdx.x == 0) {
        const float partial = s_per[0] + s_per[1] + s_per[2] + s_per[3];
        const unsigned lo = __float_as_uint(partial);
        const unsigned long long u =
            (unsigned long long)lo | ((unsigned long long)(~lo) << 32);
        atomicExch(&slots[blockIdx.x], u);       // RMW-store at coherence point
    }

    // Block 0: spin until every slot validates, then fixed-tree reduce.
    if (blockIdx.x == 0) {
        float v = 0.0f;
        if (threadIdx.x < NBLK) {
            unsigned long long u;
            for (;;) {
                u = atomicAdd(&slots[threadIdx.x], 0ULL);  // coherent RMW-read
                const unsigned lo = (unsigned)u;
                const unsigned hi = (unsigned)(u >> 32);
                if (hi == ~lo) break;
                __builtin_amdgcn_s_sleep(2);
            }
            v = __uint_as_float((unsigned)u);
        }
        for (int off = 32; off > 0; off >>= 1) v += __shfl_down(v, off);
        if (threadIdx.x == 0 || threadIdx.x == 64)
            s_fin[threadIdx.x >> 6] = v;         // wave0: slots 0..63, wave1: 64..127
        __syncthreads();
        if (threadIdx.x == 0)
            out[0] = (s_fin[0] + s_fin[1]) * (1.0f / 512.0f); // fp32(512+1e-8)==512
    }
}

extern "C" void kernel_launch(void* const* d_in, const int* in_sizes, int n_in,
                              void* d_out, int out_size, void* d_ws, size_t ws_size,
                              hipStream_t stream) {
    const float* pred = (const float*)d_in[0];
    const float* tgt  = (const float*)d_in[1];
    const float* vis  = (const float*)d_in[2];
    const float* cgr  = (const float*)d_in[3];
    unsigned long long* slots = (unsigned long long*)d_ws;
    float* out = (float*)d_out;

    gkl_fused<<<NBLK, TPB, 0, stream>>>(pred, tgt, vis, cgr, slots, out);
}

// Round 7
// 18.071 us; speedup vs baseline: 2.8110x; 1.2125x over previous
//
#include <hip/hip_runtime.h>

// GaussianKernelLoss on MI355X — two plain nodes (measured-best structure).
// Structure space mapped: 2 nodes = 18.0 µs < 1 node+spin 21.9 < memset+atomic
// 25.1 < cooperative 50.8. Exec is ~1 µs; the rest is per-dispatch overhead.
// Phase 1: one 256-thread block per (b,n); separable col/row float4 tables in
// LDS; bbox-limited inner loop (exact: w==0 outside radius). Phase 2: single
// wave reduces the 512 per-landmark values, plain-stores out[0].

#define BB 32
#define NN 16
#define HH 256
#define WW 256
#define BN (BB * NN)

__global__ __launch_bounds__(256) void gkl_phase1(
    const float* __restrict__ pred,   // [B,N,2]
    const float* __restrict__ tgt,    // [B,N,2]
    const float* __restrict__ vis,    // [B,N]
    const float* __restrict__ cg,     // [2,H,W]
    float* __restrict__ ws)           // [BN] per-landmark values
{
    const int bn = blockIdx.x;        // one block per (b,n)
    const int t  = threadIdx.x;

    // Invisible landmarks contribute exactly 0.
    if (vis[bn] < 0.5f) { if (t == 0) ws[bn] = 0.0f; return; }

    const float tx = tgt[bn * 2 + 0], ty = tgt[bn * 2 + 1];
    const float px = pred[bn * 2 + 0], py = pred[bn * 2 + 1];

    // Conservative bbox (w == 0 outside radius 0.2; +/-1 px FP margin).
    const float R = 0.2f;
    const int j_lo = max(0,      (int)floorf((tx - R) * 255.0f) - 1);
    const int j_hi = min(WW - 1, (int)ceilf ((tx + R) * 255.0f) + 1);
    const int i_lo = max(0,      (int)floorf((ty - R) * 255.0f) - 1);
    const int i_hi = min(HH - 1, (int)ceilf ((ty + R) * 255.0f) + 1);
    const int bw = j_hi - j_lo + 1;   // <= 106
    const int bh = i_hi - i_lo + 1;   // <= 106

    __shared__ float4 colA[128];
    __shared__ float4 rowA[128];
    __shared__ float  s_n[4], s_d[4];

    // Separable precompute: threads 0..127 columns, 128..255 rows.
    if (t < 128) {
        if (t < bw) {
            const float x   = cg[j_lo + t];            // x-coords: row 0 of plane 0
            const float dxt = x - tx, dxp = x - px;
            colA[t] = make_float4(dxt * dxt, expf(-50.0f * dxt * dxt),
                                  dxp * dxp, 0.0f);
        }
    } else {
        const int r = t - 128;
        if (r < bh) {
            const float y   = cg[HH * WW + (i_lo + r) * WW];  // y-coords: col 0 of plane 1
            const float dyt = y - ty, dyp = y - py;
            rowA[r] = make_float4(dyt * dyt, expf(-50.0f * dyt * dyt),
                                  dyp * dyp, 0.0f);
        }
    }
    __syncthreads();

    const int lane = t & 63;
    const int wid  = t >> 6;

    float num = 0.0f, den = 0.0f;
    for (int r = wid; r < bh; r += 4) {
        const float4 rv = rowA[r];                 // wave-uniform: LDS broadcast
        for (int c = lane; c < bw; c += 64) {
            const float4 cv = colA[c];
            const float d2t = cv.x + rv.x;
            const float dt  = sqrtf(d2t);
            float w = cv.y * rv.y;
            w = (dt <= 0.2f) ? w : 0.0f;           // exact reference mask
            const float dp = sqrtf(cv.z + rv.z);
            num = fmaf(w, dp, num);
            den += w;
        }
    }

    // Wave butterfly reduce, then cross-wave via LDS.
    for (int off = 32; off > 0; off >>= 1) {
        num += __shfl_down(num, off);
        den += __shfl_down(den, off);
    }
    if (lane == 0) { s_n[wid] = num; s_d[wid] = den; }
    __syncthreads();
    if (t == 0) {
        const float n_tot = s_n[0] + s_n[1] + s_n[2] + s_n[3];
        const float d_tot = s_d[0] + s_d[1] + s_d[2] + s_d[3];
        ws[bn] = n_tot / (d_tot + 1e-8f);
    }
}

__global__ __launch_bounds__(64) void gkl_phase2(
    const float* __restrict__ ws, float* __restrict__ out)
{
    const int t = threadIdx.x;       // single wave, no LDS, no barrier
    float v = 0.0f;
    #pragma unroll
    for (int i = 0; i < BN / 64; ++i) v += ws[t + 64 * i];   // coalesced
    for (int off = 32; off > 0; off >>= 1) v += __shfl_down(v, off);
    if (t == 0) out[0] = v * (1.0f / 512.0f);   // fp32(512 + 1e-8) == 512
}

extern "C" void kernel_launch(void* const* d_in, const int* in_sizes, int n_in,
                              void* d_out, int out_size, void* d_ws, size_t ws_size,
                              hipStream_t stream) {
    const float* pred = (const float*)d_in[0];
    const float* tgt  = (const float*)d_in[1];
    const float* vis  = (const float*)d_in[2];
    const float* cg   = (const float*)d_in[3];
    float* ws  = (float*)d_ws;
    float* out = (float*)d_out;

    gkl_phase1<<<BN, 256, 0, stream>>>(pred, tgt, vis, cg, ws);
    gkl_phase2<<<1, 64, 0, stream>>>(ws, out);
}